// Round 2
// baseline (104.570 us; speedup 1.0000x reference)
//
#include <hip/hip_runtime.h>

// Problem: pred (1,2,4096,4096) f32, label (1,4096,4096) i32.
// pm = (pred1 > pred0); w = 3 if (pm==0 && lb==1), 1 if (pm==1 && lb==0), else 0.
// out = mean(w). Streaming reduction: 192 MiB in, 4 B out. Memory-bound.
//
// R2: unroll x4 for MLP (12 independent 16B loads in flight per thread),
// fuse finalize via last-block ticket. ws[0]=acc, ws[1]=ticket.

__global__ void zero_ws_kernel(unsigned int* ws) {
    if (threadIdx.x == 0 && blockIdx.x == 0) { ws[0] = 0u; ws[1] = 0u; }
}

__device__ __forceinline__ unsigned int wsum4(float4 a, float4 b, int4 l) {
    unsigned int s = 0;
    {
        int pm = (b.x > a.x) ? 1 : 0;
        if (pm != l.x) s += (l.x == 1) ? 3u : ((l.x == 0) ? 1u : 0u);
    }
    {
        int pm = (b.y > a.y) ? 1 : 0;
        if (pm != l.y) s += (l.y == 1) ? 3u : ((l.y == 0) ? 1u : 0u);
    }
    {
        int pm = (b.z > a.z) ? 1 : 0;
        if (pm != l.z) s += (l.z == 1) ? 3u : ((l.z == 0) ? 1u : 0u);
    }
    {
        int pm = (b.w > a.w) ? 1 : 0;
        if (pm != l.w) s += (l.w == 1) ? 3u : ((l.w == 0) ? 1u : 0u);
    }
    return s;
}

__global__ __launch_bounds__(256) void loss_reduce_kernel(
        const float* __restrict__ pred,
        const int* __restrict__ label,
        unsigned int* __restrict__ ws,
        float* __restrict__ out,
        int n) {
    const float4* __restrict__ p0 = (const float4*)pred;        // class 0 plane
    const float4* __restrict__ p1 = (const float4*)(pred + n);  // class 1 plane
    const int4*   __restrict__ lb = (const int4*)label;

    const int nvec = n >> 2;
    const int T    = gridDim.x * blockDim.x;
    unsigned int local = 0;

    int i = blockIdx.x * blockDim.x + threadIdx.x;
    // main loop: 4 grid-stride steps unrolled -> 12 independent loads issued
    for (; i + 3 * T < nvec; i += 4 * T) {
        float4 a0 = p0[i];
        float4 a1 = p0[i + T];
        float4 a2 = p0[i + 2 * T];
        float4 a3 = p0[i + 3 * T];
        float4 b0 = p1[i];
        float4 b1 = p1[i + T];
        float4 b2 = p1[i + 2 * T];
        float4 b3 = p1[i + 3 * T];
        int4   l0 = lb[i];
        int4   l1 = lb[i + T];
        int4   l2 = lb[i + 2 * T];
        int4   l3 = lb[i + 3 * T];
        local += wsum4(a0, b0, l0);
        local += wsum4(a1, b1, l1);
        local += wsum4(a2, b2, l2);
        local += wsum4(a3, b3, l3);
    }
    // tail (empty for 4096^2 with grid 2048x256, kept for generality)
    for (; i < nvec; i += T)
        local += wsum4(p0[i], p1[i], lb[i]);

    // wave64 reduction
    #pragma unroll
    for (int off = 32; off > 0; off >>= 1)
        local += __shfl_down(local, off, 64);

    // block reduction via LDS (256 threads = 4 waves)
    __shared__ unsigned int wsum[4];
    const int lane = threadIdx.x & 63;
    const int wid  = threadIdx.x >> 6;
    if (lane == 0) wsum[wid] = local;
    __syncthreads();

    if (threadIdx.x == 0) {
        unsigned int s = wsum[0] + wsum[1] + wsum[2] + wsum[3];
        atomicAdd(&ws[0], s);
        __threadfence();  // make acc add visible before ticket
        unsigned int ticket = atomicAdd(&ws[1], 1u);
        if (ticket == gridDim.x - 1) {
            // last block: all acc adds are complete and visible
            unsigned int total = atomicAdd(&ws[0], 0u);  // atomic read
            out[0] = (float)((double)total / (double)n);
        }
    }
}

extern "C" void kernel_launch(void* const* d_in, const int* in_sizes, int n_in,
                              void* d_out, int out_size, void* d_ws, size_t ws_size,
                              hipStream_t stream) {
    const float* pred  = (const float*)d_in[0];
    const int*   label = (const int*)d_in[1];
    float*       out   = (float*)d_out;
    unsigned int* ws   = (unsigned int*)d_ws;
    const int n = in_sizes[1];  // 4096*4096 pixels

    zero_ws_kernel<<<1, 64, 0, stream>>>(ws);

    const int block = 256;
    const int grid  = 2048;  // 256 CUs x 8 blocks; 8 float4 per thread, no tail
    loss_reduce_kernel<<<grid, block, 0, stream>>>(pred, label, ws, out, n);
}

// Round 3
// 39.011 us; speedup vs baseline: 2.6805x; 2.6805x over previous
//
#include <hip/hip_runtime.h>

// Problem: pred (1,2,4096,4096) f32, label (1,4096,4096) i32.
// pm = (pred1 > pred0); w = 3 if (pm==0 && lb==1), 1 if (pm==1 && lb==0), else 0.
// out = mean(w). Streaming reduction: 192 MiB in, 4 B out. Memory-bound.
//
// R3: revert to R1's simple grid-stride loop (R2's strided unroll regressed 2x:
// trip count 2 killed compiler pipelining). Replace zero+atomic+finalize with a
// deterministic 2-kernel tree: partials[block] overwritten every call (no reset
// needed, no atomics), then a 1-block sum kernel.

__device__ __forceinline__ unsigned int wsum4(float4 a, float4 b, int4 l) {
    unsigned int s = 0;
    {
        int pm = (b.x > a.x) ? 1 : 0;
        if (pm != l.x) s += (l.x == 1) ? 3u : ((l.x == 0) ? 1u : 0u);
    }
    {
        int pm = (b.y > a.y) ? 1 : 0;
        if (pm != l.y) s += (l.y == 1) ? 3u : ((l.y == 0) ? 1u : 0u);
    }
    {
        int pm = (b.z > a.z) ? 1 : 0;
        if (pm != l.z) s += (l.z == 1) ? 3u : ((l.z == 0) ? 1u : 0u);
    }
    {
        int pm = (b.w > a.w) ? 1 : 0;
        if (pm != l.w) s += (l.w == 1) ? 3u : ((l.w == 0) ? 1u : 0u);
    }
    return s;
}

__global__ __launch_bounds__(256) void loss_partial_kernel(
        const float* __restrict__ pred,
        const int* __restrict__ label,
        unsigned int* __restrict__ partials,
        int n) {
    const float4* __restrict__ p0 = (const float4*)pred;        // class 0 plane
    const float4* __restrict__ p1 = (const float4*)(pred + n);  // class 1 plane
    const int4*   __restrict__ lb = (const int4*)label;

    const int nvec = n >> 2;
    const int T    = gridDim.x * blockDim.x;
    unsigned int local = 0;

    for (int i = blockIdx.x * blockDim.x + threadIdx.x; i < nvec; i += T)
        local += wsum4(p0[i], p1[i], lb[i]);

    // wave64 reduction
    #pragma unroll
    for (int off = 32; off > 0; off >>= 1)
        local += __shfl_down(local, off, 64);

    // block reduction via LDS (256 threads = 4 waves)
    __shared__ unsigned int wsum[4];
    const int lane = threadIdx.x & 63;
    const int wid  = threadIdx.x >> 6;
    if (lane == 0) wsum[wid] = local;
    __syncthreads();
    if (threadIdx.x == 0)
        partials[blockIdx.x] = wsum[0] + wsum[1] + wsum[2] + wsum[3];
}

__global__ __launch_bounds__(256) void loss_final_kernel(
        const unsigned int* __restrict__ partials,
        float* __restrict__ out,
        int nblocks, int n) {
    unsigned int local = 0;
    for (int i = threadIdx.x; i < nblocks; i += 256)
        local += partials[i];

    #pragma unroll
    for (int off = 32; off > 0; off >>= 1)
        local += __shfl_down(local, off, 64);

    __shared__ unsigned int wsum[4];
    const int lane = threadIdx.x & 63;
    const int wid  = threadIdx.x >> 6;
    if (lane == 0) wsum[wid] = local;
    __syncthreads();
    if (threadIdx.x == 0) {
        unsigned int total = wsum[0] + wsum[1] + wsum[2] + wsum[3];
        out[0] = (float)((double)total / (double)n);
    }
}

extern "C" void kernel_launch(void* const* d_in, const int* in_sizes, int n_in,
                              void* d_out, int out_size, void* d_ws, size_t ws_size,
                              hipStream_t stream) {
    const float* pred  = (const float*)d_in[0];
    const int*   label = (const int*)d_in[1];
    float*       out   = (float*)d_out;
    unsigned int* partials = (unsigned int*)d_ws;  // 2048 * 4 B = 8 KB scratch
    const int n = in_sizes[1];  // 4096*4096 pixels

    const int block = 256;
    const int grid  = 2048;  // 256 CUs x 8 blocks; 8 float4 per thread, no tail

    loss_partial_kernel<<<grid, block, 0, stream>>>(pred, label, partials, n);
    loss_final_kernel<<<1, block, 0, stream>>>(partials, out, grid, n);
}

// Round 4
// 35.551 us; speedup vs baseline: 2.9414x; 1.0973x over previous
//
#include <hip/hip_runtime.h>

// Problem: pred (1,2,4096,4096) f32, label (1,4096,4096) i32.
// pm = (pred1 > pred0); w = 3 if (pm==0 && lb==1), 1 if (pm==1 && lb==0), else 0.
// out = mean(w). Streaming reduction: 192 MiB in, 4 B out. Memory-bound.
//
// R4: block-contiguous x2 unroll (6 loads in flight/thread, streams 4 KB apart,
// trip count 4 — unlike R2's 8 MiB-strided unroll that killed pipelining).
// Final reduce = 1 wave, uint4 loads. 2 dispatches, no atomics, replay-safe
// (partials fully overwritten each call).

__device__ __forceinline__ unsigned int wsum4(float4 a, float4 b, int4 l) {
    unsigned int s = 0;
    {
        int pm = (b.x > a.x) ? 1 : 0;
        if (pm != l.x) s += (l.x == 1) ? 3u : ((l.x == 0) ? 1u : 0u);
    }
    {
        int pm = (b.y > a.y) ? 1 : 0;
        if (pm != l.y) s += (l.y == 1) ? 3u : ((l.y == 0) ? 1u : 0u);
    }
    {
        int pm = (b.z > a.z) ? 1 : 0;
        if (pm != l.z) s += (l.z == 1) ? 3u : ((l.z == 0) ? 1u : 0u);
    }
    {
        int pm = (b.w > a.w) ? 1 : 0;
        if (pm != l.w) s += (l.w == 1) ? 3u : ((l.w == 0) ? 1u : 0u);
    }
    return s;
}

__global__ __launch_bounds__(256) void loss_partial_kernel(
        const float* __restrict__ pred,
        const int* __restrict__ label,
        unsigned int* __restrict__ partials,
        int n) {
    const float4* __restrict__ p0 = (const float4*)pred;        // class 0 plane
    const float4* __restrict__ p1 = (const float4*)(pred + n);  // class 1 plane
    const int4*   __restrict__ lb = (const int4*)label;

    const int nvec = n >> 2;                 // 4M float4
    const int step = gridDim.x * 512;        // each block: contiguous 512-float4 chunk
    unsigned int local = 0;

    int i = blockIdx.x * 512 + threadIdx.x;
    for (; i + 256 < nvec; i += step) {
        float4 a0 = p0[i];
        float4 a1 = p0[i + 256];
        float4 b0 = p1[i];
        float4 b1 = p1[i + 256];
        int4   l0 = lb[i];
        int4   l1 = lb[i + 256];
        local += wsum4(a0, b0, l0);
        local += wsum4(a1, b1, l1);
    }
    if (i < nvec)  // generic tail (empty at 4096^2 with grid 2048)
        local += wsum4(p0[i], p1[i], lb[i]);

    // wave64 reduction
    #pragma unroll
    for (int off = 32; off > 0; off >>= 1)
        local += __shfl_down(local, off, 64);

    // block reduction via LDS (256 threads = 4 waves)
    __shared__ unsigned int wsum[4];
    const int lane = threadIdx.x & 63;
    const int wid  = threadIdx.x >> 6;
    if (lane == 0) wsum[wid] = local;
    __syncthreads();
    if (threadIdx.x == 0)
        partials[blockIdx.x] = wsum[0] + wsum[1] + wsum[2] + wsum[3];
}

__global__ __launch_bounds__(64) void loss_final_kernel(
        const unsigned int* __restrict__ partials,
        float* __restrict__ out,
        int nblocks, int n) {
    const uint4* __restrict__ p4 = (const uint4*)partials;
    const int nv = nblocks >> 2;             // 512 uint4
    unsigned int local = 0;
    for (int i = threadIdx.x; i < nv; i += 64) {
        uint4 v = p4[i];
        local += v.x + v.y + v.z + v.w;
    }
    #pragma unroll
    for (int off = 32; off > 0; off >>= 1)
        local += __shfl_down(local, off, 64);
    if (threadIdx.x == 0)
        out[0] = (float)((double)local / (double)n);
}

extern "C" void kernel_launch(void* const* d_in, const int* in_sizes, int n_in,
                              void* d_out, int out_size, void* d_ws, size_t ws_size,
                              hipStream_t stream) {
    const float* pred  = (const float*)d_in[0];
    const int*   label = (const int*)d_in[1];
    float*       out   = (float*)d_out;
    unsigned int* partials = (unsigned int*)d_ws;  // 2048 * 4 B = 8 KB scratch
    const int n = in_sizes[1];  // 4096*4096 pixels

    const int block = 256;
    const int grid  = 2048;  // 256 CUs x 8 blocks; 4 unrolled iters/thread, no tail

    loss_partial_kernel<<<grid, block, 0, stream>>>(pred, label, partials, n);
    loss_final_kernel<<<1, 64, 0, stream>>>(partials, out, grid, n);
}